// Round 13
// baseline (1026.288 us; speedup 1.0000x reference)
//
#include <hip/hip_runtime.h>
#include <hip/hip_bf16.h>
#include <math.h>
#include <type_traits>

#define SEQ  512
#define BSZ  128
#define EMBD 128
#define H4   512
#define HD   128
#define NTAG 7
#define BOSX 4
#define EOSX 5
#define NEGC (-10000.0f)
#define TILE 16

typedef _Float16 h2 __attribute__((ext_vector_type(2)));

template<typename T> __device__ __forceinline__ void stf(T* p, float v);
template<> __device__ __forceinline__ void stf<float>(float* p, float v) { *p = v; }
template<> __device__ __forceinline__ void stf<__hip_bfloat16>(__hip_bfloat16* p, float v) { *p = __float2bfloat16(v); }

__device__ __forceinline__ float frcp(float x) { return __builtin_amdgcn_rcpf(x); }
__device__ __forceinline__ float bflo(unsigned d) { return __builtin_bit_cast(float, d << 16); }
__device__ __forceinline__ float bfhi(unsigned d) { return __builtin_bit_cast(float, d & 0xFFFF0000u); }

// f16 dot2: 2 MACs/inst, fp32 accumulate (v_dot2_f32_f16)
__device__ __forceinline__ float fdot2(h2 a, h2 b, float c) {
#if __has_builtin(__builtin_amdgcn_fdot2)
    return __builtin_amdgcn_fdot2(a, b, c, false);
#else
    return c + (float)a.x * (float)b.x + (float)a.y * (float)b.y;
#endif
}

template<int C> __device__ __forceinline__ float dppaddf(float x) {
    const int y = __builtin_amdgcn_update_dpp(0, __builtin_bit_cast(int, x), C, 0xF, 0xF, true);
    return x + __builtin_bit_cast(float, y);
}
template<int C> __device__ __forceinline__ float dppmovf(float x) {
    return __builtin_bit_cast(float,
        __builtin_amdgcn_update_dpp(0, __builtin_bit_cast(int, x), C, 0xF, 0xF, true));
}
// k = lane bits {0,1}: full k-reduce = 2 DPP stages
__device__ __forceinline__ float kreduce4(float x) {
    x = dppaddf<0xB1>(x);   // xor bit0
    x = dppaddf<0x4E>(x);   // xor bit1
    return x;
}

// f16 chunk layout: chunk k = 32 f16 = 16 dwords at dword offset 20*k.
// Within one b128 read (sub-offset 4j) the wave's 4 distinct chunk addresses
// hit disjoint bank quads -> conflict-free; 16 lanes per address broadcast.
#define CH_DW  20
#define ROW_DW 80

// 32-element f16 chunk dot: w[16] half2 x x[16] half2 -> fp32
__device__ __forceinline__ float dot32h(const h2* __restrict__ w, const h2* __restrict__ x) {
    float a = 0.f;
    #pragma unroll
    for (int j = 0; j < 16; ++j) a = fdot2(w[j], x[j], a);
    return a;
}
// load 32 fp32 weights -> 16 half2 (RNE, one-time)
__device__ __forceinline__ void ldwh(h2* w, const float4* wr) {
    #pragma unroll
    for (int j = 0; j < 8; ++j) {
        const float4 f4 = wr[j];
        h2 a; a.x = (_Float16)f4.x; a.y = (_Float16)f4.y;
        h2 b; b.x = (_Float16)f4.z; b.y = (_Float16)f4.w;
        w[2 * j] = a; w[2 * j + 1] = b;
    }
}
__device__ __forceinline__ void unp16(const uint4* p, h2* x) {
    #pragma unroll
    for (int j = 0; j < 4; ++j) {
        x[4 * j]     = __builtin_bit_cast(h2, p[j].x);
        x[4 * j + 1] = __builtin_bit_cast(h2, p[j].y);
        x[4 * j + 2] = __builtin_bit_cast(h2, p[j].z);
        x[4 * j + 3] = __builtin_bit_cast(h2, p[j].w);
    }
}

// ======================= K1: input projection =======================
// grid 2*BSZ (1 block/CU), block 512 = 8 waves (R11 phase A, unchanged).
// Separate kernel so it keeps 256-CU parallelism while K2 packs 2 chains/CU.
template<typename XWT>
__global__ __launch_bounds__(512) __attribute__((amdgpu_waves_per_eu(2, 2)))
void proj_kernel(const int* __restrict__ sen, const float* __restrict__ emb,
                 const float* __restrict__ Wih_f, const float* __restrict__ b_f,
                 const float* __restrict__ Wih_b, const float* __restrict__ b_b,
                 XWT* __restrict__ xw)
{
    const int tid = threadIdx.x;
    const int wid = tid >> 6;
    const int lane = tid & 63;
    const int k = lane & 3;
    const int m = lane >> 2;
    const int u = wid * 16 + m;
    const bool bk0 = (lane & 1) != 0;
    const bool bk1 = (lane & 2) != 0;
    const int chain = blockIdx.x;
    const int dir = chain & 1;
    const int b = chain >> 1;
    const float* __restrict__ Wih  = dir ? Wih_b : Wih_f;
    const float* __restrict__ bias = dir ? b_b : b_f;

    __shared__ __align__(16) unsigned smem_u[32 * ROW_DW];

    h2 w2[4][16];                                          // 64 VGPRs f16 weights
    #pragma unroll
    for (int g = 0; g < 4; ++g)
        ldwh(w2[g], (const float4*)(Wih + (g * HD + u) * EMBD + k * 32));
    const float bj = bias[k * HD + u];
    XWT* __restrict__ xw_c = xw + (size_t)chain * (SEQ * H4);

    for (int tt = 0; tt < SEQ; tt += 32) {
        {   // stage 32 embedding rows as f16 chunks: 16 threads/row x 8 floats.
            // Thread p carries elements [8p,8p+8) = 4 dwords -> chunk p>>2,
            // dword offset (p&3)*4. (R12's (p>>3)/(p&7)*2 left chunks 2..7
            // uninitialized -> NaN. This is the verified R11 mapping.)
            const int srow = tid >> 4;
            const int p = tid & 15;
            const int tok = sen[(tt + srow) * BSZ + b];
            const float4* er = (const float4*)(emb + (size_t)tok * EMBD + p * 8);
            const float4 v0 = er[0], v1 = er[1];
            uint4 dd;
            h2 t;
            t.x = (_Float16)v0.x; t.y = (_Float16)v0.y; dd.x = __builtin_bit_cast(unsigned, t);
            t.x = (_Float16)v0.z; t.y = (_Float16)v0.w; dd.y = __builtin_bit_cast(unsigned, t);
            t.x = (_Float16)v1.x; t.y = (_Float16)v1.y; dd.z = __builtin_bit_cast(unsigned, t);
            t.x = (_Float16)v1.z; t.y = (_Float16)v1.w; dd.w = __builtin_bit_cast(unsigned, t);
            *(uint4*)&smem_u[srow * ROW_DW + (p >> 2) * CH_DW + (p & 3) * 4] = dd;
        }
        __syncthreads();
        for (int i = 0; i < 32; ++i) {
            const uint4* xr = (const uint4*)(smem_u + i * ROW_DW + k * CH_DW);
            uint4 pk[4];
            #pragma unroll
            for (int j = 0; j < 4; ++j) pk[j] = xr[j];
            h2 hx[16];
            unp16(pk, hx);
            const float pi = dot32h(w2[0], hx);
            const float pf = dot32h(w2[1], hx);
            const float pg = dot32h(w2[2], hx);
            const float po = dot32h(w2[3], hx);
            const float A = (bk0 ? pf : pi) + dppmovf<0xB1>(bk0 ? pi : pf);
            const float B = (bk0 ? po : pg) + dppmovf<0xB1>(bk0 ? pg : po);
            const float z = (bk1 ? B : A) + dppmovf<0x4E>(bk1 ? A : B);
            stf(&xw_c[(tt + i) * H4 + u * 4 + k], z + bj);
        }
        __syncthreads();
    }
}

// ======================= K2: recurrence + emissions =======================
// grid BSZ (=128 blocks), block 1024 = TWO chains (fwd+bwd of batch b) x
// 8 waves each. R11 data: 256 chains on 256 CUs left a ~1550 cyc/step cost
// that halving waves didn't touch, VALUBusy 64% -> pack 2 independent chains
// per CU so each chain's stall windows are filled by the other's issue.
// Per-chain logic identical to R11 phase B (k=4-way, f16 weights in VGPRs).
template<typename XWT>
__global__ __launch_bounds__(1024) __attribute__((amdgpu_waves_per_eu(4, 4)))
void rec_kernel(const float* __restrict__ Whh_f, const float* __restrict__ Whh_b,
                const float* __restrict__ W_out,
                const XWT* __restrict__ xw,
                float* __restrict__ eft, float* __restrict__ ebt)
{
    const int cid = threadIdx.x >> 9;                      // chain within block (=dir)
    const int tid = threadIdx.x & 511;                     // per-chain thread id
    const int wid = tid >> 6;
    const int lane = tid & 63;
    const int k = lane & 3;
    const int m = lane >> 2;
    const int u = wid * 16 + m;
    const bool bk0 = (lane & 1) != 0;
    const bool bk1 = (lane & 2) != 0;
    const int dir = cid;
    const int b = blockIdx.x;
    const int chain = b * 2 + dir;
    const float* __restrict__ Whh = dir ? Whh_b : Whh_f;

    __shared__ __align__(16) unsigned smem_u[2][TILE * H4];  // 64 KB xw tiles
    __shared__ __align__(16) unsigned hdb_u[2][2 * ROW_DW];  // h dbuf per chain

    h2 w2[4][16];                                          // 64 VGPRs f16 weights
    #pragma unroll
    for (int g = 0; g < 4; ++g)
        ldwh(w2[g], (const float4*)(Whh + (g * HD + u) * HD + k * 32));
    h2 wo[16];                                             // wave-0 emission weights
    {
        const int mm = (m < NTAG) ? m : 0;
        ldwh(wo, (const float4*)(W_out + mm * 256 + dir * HD + k * 32));
    }
    if (tid < 2 * ROW_DW) hdb_u[cid][tid] = 0u;            // h=0
    float c = 0.0f, v0 = 0.0f, v1 = 0.0f, v2 = 0.0f, v3 = 0.0f;
    const XWT* __restrict__ xw_c = xw + (size_t)chain * (SEQ * H4);
    float* __restrict__ eX = (dir ? ebt : eft) + (size_t)b * (SEQ * 8);
    float (*xwt)[H4] = (float (*)[H4])smem_u[cid];
    __syncthreads();

    const int t0 = dir ? (SEQ - 1) : 0;
    const int ts = dir ? -1 : 1;
    for (int s = 0; s <= SEQ; ++s) {
        if ((s & (TILE - 1)) == 0) {
            if (s < SEQ) {                                 // wave wid stages slots 2wid,2wid+1
                #pragma unroll
                for (int sl = 0; sl < 2; ++sl) {
                    const int slot = wid * 2 + sl;
                    const int tg = t0 + ts * (s + slot);
                    float4* dst = (float4*)xwt[slot];
                    if constexpr (std::is_same_v<XWT, float>) {
                        const float4* src = (const float4*)(xw_c + tg * H4);
                        dst[lane] = src[lane];
                        dst[lane + 64] = src[lane + 64];
                    } else {
                        const uint4 raw = ((const uint4*)(xw_c + tg * H4))[lane];
                        const unsigned rr[4] = {raw.x, raw.y, raw.z, raw.w};
                        float4 lo4, hi4;
                        float* lp = (float*)&lo4; float* hp = (float*)&hi4;
                        #pragma unroll
                        for (int j = 0; j < 2; ++j) {
                            lp[2*j]   = bflo(rr[j]);
                            lp[2*j+1] = bfhi(rr[j]);
                            hp[2*j]   = bflo(rr[j+2]);
                            hp[2*j+1] = bfhi(rr[j+2]);
                        }
                        dst[2 * lane] = lo4;
                        dst[2 * lane + 1] = hi4;
                    }
                }
            }
            __syncthreads();
        }
        const int cur = s & 1;
        h2 hx[16];                                         // chunk k of h_{t-ts}
        {
            const uint4* hr = (const uint4*)(hdb_u[cid] + cur * ROW_DW + k * CH_DW);
            uint4 pk[4];
            #pragma unroll
            for (int j = 0; j < 4; ++j) pk[j] = hr[j];
            unp16(pk, hx);
        }
        if (s < SEQ) {
            const float xq = xwt[s & (TILE - 1)][u * 4 + k];
            const float pi = dot32h(w2[0], hx);
            const float pf = dot32h(w2[1], hx);
            const float pg = dot32h(w2[2], hx);
            const float po = dot32h(w2[3], hx);
            const float A = (bk0 ? pf : pi) + dppmovf<0xB1>(bk0 ? pi : pf);
            const float B = (bk0 ? po : pg) + dppmovf<0xB1>(bk0 ? pg : po);
            float z = (bk1 ? B : A) + dppmovf<0x4E>(bk1 ? A : B);
            z += xq;
            const bool isg = bk1 && !bk0;
            const float x2 = isg ? (z + z) : z;
            float y = frcp(1.0f + __expf(-x2));
            y = isg ? (2.0f * y - 1.0f) : y;
            const float r1 = dppmovf<0xB1>(y);
            const float r2 = dppmovf<0x4E>(y);
            const float r3 = dppmovf<0x4E>(r1);
            const float i0 = bk0 ? r1 : y,  i1 = bk0 ? y : r1;
            const float i2 = bk0 ? r3 : r2, i3 = bk0 ? r2 : r3;
            const float gi = bk1 ? i2 : i0;
            const float gf = bk1 ? i3 : i1;
            const float gg = bk1 ? i0 : i2;
            const float go = bk1 ? i1 : i3;
            c = gf * c + gi * gg;
            const float th = 2.0f * frcp(1.0f + __expf(-2.0f * c)) - 1.0f;
            const float h = go * th;
            if (k == 0) {
                ((unsigned short*)hdb_u[cid])[((cur ^ 1) * ROW_DW + (u >> 5) * CH_DW) * 2 + (u & 31)]
                    = __builtin_bit_cast(unsigned short, (_Float16)h);
            }
        }
        if (wid == 0 && s >= 1) {                          // emission for time e = s-1
            const float ev = kreduce4(dot32h(wo, hx));
            const int e = s - 1;
            const bool mine = (e & 3) == k;
            const int j = (e >> 2) & 3;
            v0 = (mine && j == 0) ? ev : v0;
            v1 = (mine && j == 1) ? ev : v1;
            v2 = (mine && j == 2) ? ev : v2;
            v3 = (mine && j == 3) ? ev : v3;
            if ((s & (TILE - 1)) == 0 && m < NTAG) {
                const int eA = s - TILE + k;
                eX[(t0 + ts * (eA +  0)) * 8 + m] = v0;
                eX[(t0 + ts * (eA +  4)) * 8 + m] = v1;
                eX[(t0 + ts * (eA +  8)) * 8 + m] = v2;
                eX[(t0 + ts * (eA + 12)) * 8 + m] = v3;
            }
        }
        __syncthreads();
    }
}

// ======================= K3: Viterbi scan + backtrace =======================
__global__ __launch_bounds__(256, 1)
void vit_kernel(const float* __restrict__ eft, const float* __restrict__ ebt,
                const float* __restrict__ b_out, const float* __restrict__ trans,
                float* __restrict__ out)
{
    const int b = blockIdx.x;
    const int tid = threadIdx.x;
    __shared__ __align__(16) float ftl[SEQ * 8];
    __shared__ int bptr_lds[SEQ * 8];
    __shared__ unsigned char path[SEQ * 8];
    __shared__ int sbest;

    {
        const float4* sf = (const float4*)(eft + (size_t)b * (SEQ * 8));
        const float4* sb = (const float4*)(ebt + (size_t)b * (SEQ * 8));
        float4* dst = (float4*)ftl;
        #pragma unroll
        for (int i = 0; i < SEQ * 2 / 256; ++i) {
            const int idx = tid + i * 256;
            float4 a = sf[idx];
            const float4 c4 = sb[idx];
            a.x += c4.x; a.y += c4.y; a.z += c4.z; a.w += c4.w;
            dst[idx] = a;
        }
    }
    __syncthreads();

    if (tid < 64) {
        const int lane = tid;
        const int next = lane >> 3;
        const int prev = lane & 7;
        const bool pv = (prev < NTAG);
        const bool nv = (next < NTAG);
        const float trv = (pv && nv) ? (trans[next * NTAG + prev] + b_out[next]) : -3.0e38f;
        float fvp = pv ? ((prev == BOSX) ? 0.0f : NEGC) : -3.0e38f;
        for (int t = 0; t < SEQ; ++t) {
            float mv = fvp + trv;
            int am = prev;
            #pragma unroll
            for (int off = 1; off < 8; off <<= 1) {        // first-max-index semantics
                const float om = __shfl_xor(mv, off);
                const int oa = __shfl_xor(am, off);
                if (om > mv || (om == mv && oa < am)) { mv = om; am = oa; }
            }
            const float fvnew = mv + ftl[t * 8 + next];
            if (prev == 0) bptr_lds[t * 8 + next] = am;
            fvp = __shfl(fvnew, prev << 3);
            if (!pv) fvp = -3.0e38f;
        }
        float term = pv ? (fvp + trans[EOSX * NTAG + prev]) : -3.0e38f;
        int am = prev;
        #pragma unroll
        for (int off = 1; off < 8; off <<= 1) {
            const float om = __shfl_xor(term, off);
            const int oa = __shfl_xor(am, off);
            if (om > term || (om == term && oa < am)) { term = om; am = oa; }
        }
        if (lane == 0) { out[b] = term; sbest = am; }
    }
    __syncthreads();

    if (tid < NTAG) {
        int cur = tid;
        for (int t = SEQ - 1; t >= 0; --t) {
            path[t * 8 + tid] = (unsigned char)cur;
            cur = bptr_lds[t * 8 + cur];
        }
    }
    __syncthreads();
    const int am = sbest;
    for (int t = tid; t < SEQ; t += 256)
        out[BSZ + t * BSZ + b] = (float)path[t * 8 + am];
}

// ======================= launch =======================
extern "C" void kernel_launch(void* const* d_in, const int* in_sizes, int n_in,
                              void* d_out, int out_size, void* d_ws, size_t ws_size,
                              hipStream_t stream)
{
    const int*   sen   = (const int*)d_in[0];
    const float* emb   = (const float*)d_in[1];
    const float* Wih_f = (const float*)d_in[2];
    const float* Whh_f = (const float*)d_in[3];
    const float* b_f   = (const float*)d_in[4];
    const float* Wih_b = (const float*)d_in[5];
    const float* Whh_b = (const float*)d_in[6];
    const float* b_b   = (const float*)d_in[7];
    const float* W_out = (const float*)d_in[8];
    const float* b_out = (const float*)d_in[9];
    const float* trans = (const float*)d_in[10];
    float* out = (float*)d_out;

    char* ws = (char*)d_ws;
    const size_t xw_elems = (size_t)2 * BSZ * SEQ * H4;   // 67,108,864
    const size_t ft_bytes = (size_t)BSZ * SEQ * 8 * 4;    // 2 MB each

    if (ws_size >= xw_elems * 4 + 2 * ft_bytes) {
        float* xw = (float*)ws;
        float* eft = (float*)(ws + xw_elems * 4);
        float* ebt = (float*)(ws + xw_elems * 4 + ft_bytes);
        proj_kernel<float><<<dim3(2 * BSZ), dim3(512), 0, stream>>>(
            sen, emb, Wih_f, b_f, Wih_b, b_b, xw);
        rec_kernel<float><<<dim3(BSZ), dim3(1024), 0, stream>>>(
            Whh_f, Whh_b, W_out, xw, eft, ebt);
        vit_kernel<<<dim3(BSZ), dim3(256), 0, stream>>>(eft, ebt, b_out, trans, out);
    } else {
        __hip_bfloat16* xw = (__hip_bfloat16*)ws;
        float* eft = (float*)(ws + xw_elems * 2);
        float* ebt = (float*)(ws + xw_elems * 2 + ft_bytes);
        proj_kernel<__hip_bfloat16><<<dim3(2 * BSZ), dim3(512), 0, stream>>>(
            sen, emb, Wih_f, b_f, Wih_b, b_b, xw);
        rec_kernel<__hip_bfloat16><<<dim3(BSZ), dim3(1024), 0, stream>>>(
            Whh_f, Whh_b, W_out, xw, eft, ebt);
        vit_kernel<<<dim3(BSZ), dim3(256), 0, stream>>>(eft, ebt, b_out, trans, out);
    }
}